// Round 2
// baseline (2356.254 us; speedup 1.0000x reference)
//
#include <hip/hip_runtime.h>
#include <math.h>

#define BB 8
#define SS 2048
#define DDIM 512
#define EPSV 1e-6f
#define SCALE 0.044194173824159216f   // 1/sqrt(512)
#define TS 8

// ---------- k0: weight transposes ----------
__global__ __launch_bounds__(256) void k0_prep(
    const float* __restrict__ conv_w, const float* __restrict__ Wq,
    const float* __restrict__ Wk, const float* __restrict__ Wv,
    float* __restrict__ wcT, float* __restrict__ wqT,
    float* __restrict__ wkT, float* __restrict__ wvT)
{
    int idx = blockIdx.x * 256 + threadIdx.x;
    if (idx < DDIM * DDIM * 3) {
        int o = idx / (DDIM * 3);
        int r = idx - o * (DDIM * 3);     // r = i*3 + t
        wcT[(size_t)r * DDIM + o] = conv_w[idx];
    }
    if (idx < DDIM * DDIM) {
        int e = idx / DDIM, d = idx - e * DDIM;
        wqT[(size_t)d * DDIM + e] = Wq[idx];
        wkT[(size_t)d * DDIM + e] = Wk[idx];
        wvT[(size_t)d * DDIM + e] = Wv[idx];
    }
}

// ---------- k1: conv + rmsnorm + qkv + rmsnorm(q,k) + rope ----------
__global__ __launch_bounds__(256) void k1_conv_qkv(
    const float* __restrict__ x, const float* __restrict__ conv_b,
    const float* __restrict__ pre_g, const float* __restrict__ q_g,
    const float* __restrict__ k_g,
    const float* __restrict__ wcT, const float* __restrict__ wqT,
    const float* __restrict__ wkT, const float* __restrict__ wvT,
    float* __restrict__ q_out,    // [B][S][D]
    float* __restrict__ kT_out,   // [B][D][S]
    float* __restrict__ v_out)    // [B][S][D]
{
    const int t  = threadIdx.x;
    const int s0 = blockIdx.x * TS;
    const int b  = blockIdx.y;
    const int c0 = 2 * t;
    __shared__ float xs[TS + 2][DDIM];
    __shared__ float red[TS], red2[TS];

    const float* xb = x + (size_t)b * SS * DDIM;
    for (int idx = t; idx < (TS + 2) * DDIM; idx += 256) {
        int r = idx >> 9, c = idx & (DDIM - 1);
        int srow = s0 - 1 + r;
        xs[r][c] = (srow >= 0 && srow < SS) ? xb[(size_t)srow * DDIM + c] : 0.0f;
    }
    if (t < TS) red[t] = 0.0f;
    __syncthreads();

    // conv
    float acc[TS][2];
    {
        float cb0 = conv_b[c0], cb1 = conv_b[c0 + 1];
        #pragma unroll
        for (int r = 0; r < TS; r++) { acc[r][0] = cb0; acc[r][1] = cb1; }
    }
    for (int i = 0; i < DDIM; i++) {
        float xv[TS + 2];
        #pragma unroll
        for (int r = 0; r < TS + 2; r++) xv[r] = xs[r][i];
        #pragma unroll
        for (int dt = 0; dt < 3; dt++) {
            float2 w = *reinterpret_cast<const float2*>(&wcT[(size_t)(i * 3 + dt) * DDIM + c0]);
            #pragma unroll
            for (int r = 0; r < TS; r++) {
                acc[r][0] = fmaf(xv[r + dt], w.x, acc[r][0]);
                acc[r][1] = fmaf(xv[r + dt], w.y, acc[r][1]);
            }
        }
    }
    // rmsnorm of conv rows
    #pragma unroll
    for (int r = 0; r < TS; r++) {
        float p = acc[r][0] * acc[r][0] + acc[r][1] * acc[r][1];
        #pragma unroll
        for (int off = 1; off < 64; off <<= 1) p += __shfl_xor(p, off, 64);
        if ((t & 63) == 0) atomicAdd(&red[r], p);
    }
    __syncthreads();
    {
        float pg0 = pre_g[c0], pg1 = pre_g[c0 + 1];
        #pragma unroll
        for (int r = 0; r < TS; r++) {
            float inv = rsqrtf(red[r] * (1.0f / DDIM) + EPSV);
            xs[r][c0]     = acc[r][0] * inv * pg0;
            xs[r][c0 + 1] = acc[r][1] * inv * pg1;
        }
    }
    __syncthreads();

    // qkv projections
    if (t < TS) { red[t] = 0.0f; red2[t] = 0.0f; }
    float aq[TS][2] = {}, ak[TS][2] = {}, av[TS][2] = {};
    for (int d = 0; d < DDIM; d++) {
        float xv[TS];
        #pragma unroll
        for (int r = 0; r < TS; r++) xv[r] = xs[r][d];
        float2 wq = *reinterpret_cast<const float2*>(&wqT[(size_t)d * DDIM + c0]);
        float2 wk = *reinterpret_cast<const float2*>(&wkT[(size_t)d * DDIM + c0]);
        float2 wv = *reinterpret_cast<const float2*>(&wvT[(size_t)d * DDIM + c0]);
        #pragma unroll
        for (int r = 0; r < TS; r++) {
            aq[r][0] = fmaf(xv[r], wq.x, aq[r][0]); aq[r][1] = fmaf(xv[r], wq.y, aq[r][1]);
            ak[r][0] = fmaf(xv[r], wk.x, ak[r][0]); ak[r][1] = fmaf(xv[r], wk.y, ak[r][1]);
            av[r][0] = fmaf(xv[r], wv.x, av[r][0]); av[r][1] = fmaf(xv[r], wv.y, av[r][1]);
        }
    }
    // store v
    {
        float* vb = v_out + ((size_t)b * SS + s0) * DDIM;
        #pragma unroll
        for (int r = 0; r < TS; r++)
            *reinterpret_cast<float2*>(&vb[(size_t)r * DDIM + c0]) = make_float2(av[r][0], av[r][1]);
    }
    __syncthreads();
    // rmsnorm q, k
    #pragma unroll
    for (int r = 0; r < TS; r++) {
        float pq = aq[r][0] * aq[r][0] + aq[r][1] * aq[r][1];
        float pk = ak[r][0] * ak[r][0] + ak[r][1] * ak[r][1];
        #pragma unroll
        for (int off = 1; off < 64; off <<= 1) {
            pq += __shfl_xor(pq, off, 64);
            pk += __shfl_xor(pk, off, 64);
        }
        if ((t & 63) == 0) { atomicAdd(&red[r], pq); atomicAdd(&red2[r], pk); }
    }
    __syncthreads();
    // rope + stores
    float invf = (float)pow(10000.0, -(double)(2 * t) / (double)DDIM);
    float qg0 = q_g[c0], qg1 = q_g[c0 + 1];
    float kg0 = k_g[c0], kg1 = k_g[c0 + 1];
    float k0p[TS], k1p[TS];
    float* qb = q_out + ((size_t)b * SS + s0) * DDIM;
    #pragma unroll
    for (int r = 0; r < TS; r++) {
        float invq = rsqrtf(red[r] * (1.0f / DDIM) + EPSV);
        float invk = rsqrtf(red2[r] * (1.0f / DDIM) + EPSV);
        float q0 = aq[r][0] * invq * qg0, q1 = aq[r][1] * invq * qg1;
        float kk0 = ak[r][0] * invk * kg0, kk1 = ak[r][1] * invk * kg1;
        float fr = (float)(s0 + r) * invf;
        float sn, cs;
        sincosf(fr, &sn, &cs);
        *reinterpret_cast<float2*>(&qb[(size_t)r * DDIM + c0]) =
            make_float2(q0 * cs - q1 * sn, q0 * sn + q1 * cs);
        k0p[r] = kk0 * cs - kk1 * sn;
        k1p[r] = kk0 * sn + kk1 * cs;
    }
    {
        float* kTb = kT_out + (size_t)b * DDIM * SS;
        float4* p0 = reinterpret_cast<float4*>(&kTb[(size_t)c0 * SS + s0]);
        p0[0] = make_float4(k0p[0], k0p[1], k0p[2], k0p[3]);
        p0[1] = make_float4(k0p[4], k0p[5], k0p[6], k0p[7]);
        float4* p1 = reinterpret_cast<float4*>(&kTb[(size_t)(c0 + 1) * SS + s0]);
        p1[0] = make_float4(k1p[0], k1p[1], k1p[2], k1p[3]);
        p1[1] = make_float4(k1p[4], k1p[5], k1p[6], k1p[7]);
    }
}

// ---------- k2a: per-q-row online softmax stats (m, 1/l) ----------
__global__ __launch_bounds__(256) void k2a_ml(
    const float* __restrict__ q, const float* __restrict__ kT,
    float* __restrict__ m_out, float* __restrict__ rl_out)
{
    const int t  = threadIdx.x;
    const int tx = t & 15, ty = t >> 4;
    const int q0 = blockIdx.x * 32;
    const int b  = blockIdx.y;
    __shared__ float qs[32][36];
    __shared__ float ks[32][68];
    const float* qb  = q + ((size_t)b * SS + q0) * DDIM;
    const float* kTb = kT + (size_t)b * DDIM * SS;

    float m_run[2] = {-1e30f, -1e30f};
    float l_run[2] = {0.0f, 0.0f};

    const int qq = t >> 3, ll = t & 7;
    const int kd = t >> 4, kf = t & 15;

    for (int kt = 0; kt < SS / 64; kt++) {
        const int k0 = kt * 64;
        float sc[2][4] = {};
        for (int dc = 0; dc < DDIM / 32; dc++) {
            {
                float4 qv = *reinterpret_cast<const float4*>(&qb[(size_t)qq * DDIM + dc * 32 + 4 * ll]);
                qs[4 * ll + 0][qq] = qv.x; qs[4 * ll + 1][qq] = qv.y;
                qs[4 * ll + 2][qq] = qv.z; qs[4 * ll + 3][qq] = qv.w;
            }
            {
                float4 kv = *reinterpret_cast<const float4*>(&kTb[(size_t)(dc * 32 + kd) * SS + k0 + 4 * kf]);
                *reinterpret_cast<float4*>(&ks[kd][4 * kf]) = kv;
                float4 kv2 = *reinterpret_cast<const float4*>(&kTb[(size_t)(dc * 32 + kd + 16) * SS + k0 + 4 * kf]);
                *reinterpret_cast<float4*>(&ks[kd + 16][4 * kf]) = kv2;
            }
            __syncthreads();
            #pragma unroll
            for (int dd = 0; dd < 32; dd++) {
                float qa0 = qs[dd][ty * 2 + 0];
                float qa1 = qs[dd][ty * 2 + 1];
                float4 kv = *reinterpret_cast<const float4*>(&ks[dd][tx * 4]);
                sc[0][0] = fmaf(qa0, kv.x, sc[0][0]); sc[0][1] = fmaf(qa0, kv.y, sc[0][1]);
                sc[0][2] = fmaf(qa0, kv.z, sc[0][2]); sc[0][3] = fmaf(qa0, kv.w, sc[0][3]);
                sc[1][0] = fmaf(qa1, kv.x, sc[1][0]); sc[1][1] = fmaf(qa1, kv.y, sc[1][1]);
                sc[1][2] = fmaf(qa1, kv.z, sc[1][2]); sc[1][3] = fmaf(qa1, kv.w, sc[1][3]);
            }
            __syncthreads();
        }
        #pragma unroll
        for (int i = 0; i < 2; i++) {
            float s0v = sc[i][0] * SCALE, s1v = sc[i][1] * SCALE;
            float s2v = sc[i][2] * SCALE, s3v = sc[i][3] * SCALE;
            float tmax = fmaxf(fmaxf(s0v, s1v), fmaxf(s2v, s3v));
            #pragma unroll
            for (int off = 1; off < 16; off <<= 1) tmax = fmaxf(tmax, __shfl_xor(tmax, off, 64));
            float m_new = fmaxf(m_run[i], tmax);
            float p = __expf(s0v - m_new) + __expf(s1v - m_new) +
                      __expf(s2v - m_new) + __expf(s3v - m_new);
            #pragma unroll
            for (int off = 1; off < 16; off <<= 1) p += __shfl_xor(p, off, 64);
            l_run[i] = l_run[i] * __expf(m_run[i] - m_new) + p;
            m_run[i] = m_new;
        }
    }
    if (tx == 0) {
        #pragma unroll
        for (int i = 0; i < 2; i++) {
            int row = q0 + ty * 2 + i;
            m_out[(size_t)b * SS + row]  = m_run[i];
            rl_out[(size_t)b * SS + row] = 1.0f / l_run[i];
        }
    }
}

// ---------- k2b: column sums of softmax weights ----------
__global__ __launch_bounds__(256) void k2b_cw(
    const float* __restrict__ q, const float* __restrict__ kT,
    const float* __restrict__ m_in, const float* __restrict__ rl_in,
    float* __restrict__ cw)
{
    const int t  = threadIdx.x;
    const int tx = t & 15, ty = t >> 4;
    const int k0 = blockIdx.x * 32;
    const int b  = blockIdx.y;
    __shared__ float qs[32][68];
    __shared__ float ks[32][36];
    __shared__ float redc[16][32];
    const float* kTb = kT + (size_t)b * DDIM * SS;

    float cwacc[2] = {0.f, 0.f};
    const int qq = t >> 2, l2 = t & 3;
    const int kd = t >> 3, kf = t & 7;

    for (int qt = 0; qt < SS / 64; qt++) {
        const int qbase = qt * 64;
        const float* qb = q + ((size_t)b * SS + qbase) * DDIM;
        float mm[4], rr[4];
        #pragma unroll
        for (int i = 0; i < 4; i++) {
            int row = qbase + ty * 4 + i;
            mm[i] = m_in[(size_t)b * SS + row];
            rr[i] = rl_in[(size_t)b * SS + row];
        }
        float sc[4][2] = {};
        for (int dc = 0; dc < DDIM / 32; dc++) {
            {
                float4 qv = *reinterpret_cast<const float4*>(&qb[(size_t)qq * DDIM + dc * 32 + 4 * l2]);
                qs[4 * l2 + 0][qq] = qv.x; qs[4 * l2 + 1][qq] = qv.y;
                qs[4 * l2 + 2][qq] = qv.z; qs[4 * l2 + 3][qq] = qv.w;
                float4 qv2 = *reinterpret_cast<const float4*>(&qb[(size_t)qq * DDIM + dc * 32 + 16 + 4 * l2]);
                qs[16 + 4 * l2 + 0][qq] = qv2.x; qs[16 + 4 * l2 + 1][qq] = qv2.y;
                qs[16 + 4 * l2 + 2][qq] = qv2.z; qs[16 + 4 * l2 + 3][qq] = qv2.w;
            }
            {
                float4 kv = *reinterpret_cast<const float4*>(&kTb[(size_t)(dc * 32 + kd) * SS + k0 + 4 * kf]);
                *reinterpret_cast<float4*>(&ks[kd][4 * kf]) = kv;
            }
            __syncthreads();
            #pragma unroll
            for (int dd = 0; dd < 32; dd++) {
                float4 qa = *reinterpret_cast<const float4*>(&qs[dd][ty * 4]);
                float kb0 = ks[dd][tx * 2 + 0], kb1 = ks[dd][tx * 2 + 1];
                sc[0][0] = fmaf(qa.x, kb0, sc[0][0]); sc[0][1] = fmaf(qa.x, kb1, sc[0][1]);
                sc[1][0] = fmaf(qa.y, kb0, sc[1][0]); sc[1][1] = fmaf(qa.y, kb1, sc[1][1]);
                sc[2][0] = fmaf(qa.z, kb0, sc[2][0]); sc[2][1] = fmaf(qa.z, kb1, sc[2][1]);
                sc[3][0] = fmaf(qa.w, kb0, sc[3][0]); sc[3][1] = fmaf(qa.w, kb1, sc[3][1]);
            }
            __syncthreads();
        }
        #pragma unroll
        for (int i = 0; i < 4; i++) {
            cwacc[0] += __expf(sc[i][0] * SCALE - mm[i]) * rr[i];
            cwacc[1] += __expf(sc[i][1] * SCALE - mm[i]) * rr[i];
        }
    }
    redc[ty][tx * 2 + 0] = cwacc[0];
    redc[ty][tx * 2 + 1] = cwacc[1];
    __syncthreads();
    if (t < 32) {
        float s = 0.f;
        #pragma unroll
        for (int j = 0; j < 16; j++) s += redc[j][t];
        cw[(size_t)b * SS + k0 + t] = s;
    }
}

// ---------- k4: out = (sum_s x + sum_k cw*v) / S ----------
__global__ __launch_bounds__(256) void k4_out(
    const float* __restrict__ x, const float* __restrict__ v,
    const float* __restrict__ cwv, float* __restrict__ out)
{
    const int b = blockIdx.x, c = blockIdx.y;
    const int t = threadIdx.x;
    const int srow0 = c * (SS / 16);
    const float* xb  = x + ((size_t)b * SS + srow0) * DDIM;
    const float* vb  = v + ((size_t)b * SS + srow0) * DDIM;
    const float* cwb = cwv + (size_t)b * SS + srow0;
    float a0 = 0.f, a1 = 0.f;
    for (int r = 0; r < SS / 16; r++) {
        float w = cwb[r];
        a0 += xb[(size_t)r * DDIM + t]       + w * vb[(size_t)r * DDIM + t];
        a1 += xb[(size_t)r * DDIM + t + 256] + w * vb[(size_t)r * DDIM + t + 256];
    }
    atomicAdd(&out[b * DDIM + t],       a0 * (1.0f / SS));
    atomicAdd(&out[b * DDIM + t + 256], a1 * (1.0f / SS));
}

extern "C" void kernel_launch(void* const* d_in, const int* in_sizes, int n_in,
                              void* d_out, int out_size, void* d_ws, size_t ws_size,
                              hipStream_t stream)
{
    const float* x      = (const float*)d_in[0];
    const float* conv_w = (const float*)d_in[1];
    const float* conv_b = (const float*)d_in[2];
    const float* pre_g  = (const float*)d_in[3];
    const float* q_g    = (const float*)d_in[4];
    const float* k_g    = (const float*)d_in[5];
    const float* Wq     = (const float*)d_in[6];
    const float* Wk     = (const float*)d_in[7];
    const float* Wv     = (const float*)d_in[8];
    float* out          = (float*)d_out;

    float* ws = (float*)d_ws;
    float* wcT  = ws; ws += (size_t)DDIM * DDIM * 3;
    float* wqT  = ws; ws += (size_t)DDIM * DDIM;
    float* wkT  = ws; ws += (size_t)DDIM * DDIM;
    float* wvT  = ws; ws += (size_t)DDIM * DDIM;
    float* qbuf = ws; ws += (size_t)BB * SS * DDIM;
    float* kTb  = ws; ws += (size_t)BB * SS * DDIM;
    float* vbuf = ws; ws += (size_t)BB * SS * DDIM;
    float* mbuf = ws; ws += (size_t)BB * SS;
    float* rlb  = ws; ws += (size_t)BB * SS;
    float* cwb  = ws; ws += (size_t)BB * SS;

    (void)hipMemsetAsync(d_out, 0, (size_t)out_size * sizeof(float), stream);

    k0_prep<<<dim3((DDIM * DDIM * 3 + 255) / 256), 256, 0, stream>>>(
        conv_w, Wq, Wk, Wv, wcT, wqT, wkT, wvT);
    k1_conv_qkv<<<dim3(SS / TS, BB), 256, 0, stream>>>(
        x, conv_b, pre_g, q_g, k_g, wcT, wqT, wkT, wvT, qbuf, kTb, vbuf);
    k2a_ml<<<dim3(SS / 32, BB), 256, 0, stream>>>(qbuf, kTb, mbuf, rlb);
    k2b_cw<<<dim3(SS / 32, BB), 256, 0, stream>>>(qbuf, kTb, mbuf, rlb, cwb);
    k4_out<<<dim3(BB, 16), 256, 0, stream>>>(x, vbuf, cwb, out);
}

// Round 3
// 1027.073 us; speedup vs baseline: 2.2941x; 2.2941x over previous
//
#include <hip/hip_runtime.h>
#include <math.h>

#define BB 8
#define SS 2048
#define DDIM 512
#define EPSV 1e-6f
#define SCALE 0.044194173824159216f   // 1/sqrt(512)
#define TS 8

typedef unsigned short ushort_t;
using short8 = __attribute__((ext_vector_type(8))) short;
using f32x4  = __attribute__((ext_vector_type(4))) float;

__device__ inline unsigned short f2bf(float f) {
    union { float f; unsigned int u; } v; v.f = f;
    unsigned int r = v.u + 0x7FFFu + ((v.u >> 16) & 1u);   // RNE
    return (unsigned short)(r >> 16);
}
__device__ inline unsigned int packbf(float a, float b) {
    return (unsigned int)f2bf(a) | ((unsigned int)f2bf(b) << 16);
}
__device__ inline float bf2f(unsigned short s) {
    union { unsigned int u; float f; } v; v.u = ((unsigned int)s) << 16; return v.f;
}

// ---------- k0: weight transposes (fp32, for k1) ----------
__global__ __launch_bounds__(256) void k0_prep(
    const float* __restrict__ conv_w, const float* __restrict__ Wq,
    const float* __restrict__ Wk, const float* __restrict__ Wv,
    float* __restrict__ wcT, float* __restrict__ wqT,
    float* __restrict__ wkT, float* __restrict__ wvT)
{
    int idx = blockIdx.x * 256 + threadIdx.x;
    if (idx < DDIM * DDIM * 3) {
        int o = idx / (DDIM * 3);
        int r = idx - o * (DDIM * 3);     // r = i*3 + t
        wcT[(size_t)r * DDIM + o] = conv_w[idx];
    }
    if (idx < DDIM * DDIM) {
        int e = idx / DDIM, d = idx - e * DDIM;
        wqT[(size_t)d * DDIM + e] = Wq[idx];
        wkT[(size_t)d * DDIM + e] = Wk[idx];
        wvT[(size_t)d * DDIM + e] = Wv[idx];
    }
}

// ---------- k1: conv + rmsnorm + qkv + rmsnorm(q,k) + rope (fp32 compute, bf16 out) ----------
__global__ __launch_bounds__(256) void k1_conv_qkv(
    const float* __restrict__ x, const float* __restrict__ conv_b,
    const float* __restrict__ pre_g, const float* __restrict__ q_g,
    const float* __restrict__ k_g,
    const float* __restrict__ wcT, const float* __restrict__ wqT,
    const float* __restrict__ wkT, const float* __restrict__ wvT,
    ushort_t* __restrict__ q_out,    // [B][S][D] bf16
    ushort_t* __restrict__ k_out,    // [B][S][D] bf16
    ushort_t* __restrict__ v_out)    // [B][S][D] bf16
{
    const int t  = threadIdx.x;
    const int s0 = blockIdx.x * TS;
    const int b  = blockIdx.y;
    const int c0 = 2 * t;
    __shared__ float xs[TS + 2][DDIM];
    __shared__ float red[TS], red2[TS];

    const float* xb = x + (size_t)b * SS * DDIM;
    for (int idx = t; idx < (TS + 2) * DDIM; idx += 256) {
        int r = idx >> 9, c = idx & (DDIM - 1);
        int srow = s0 - 1 + r;
        xs[r][c] = (srow >= 0 && srow < SS) ? xb[(size_t)srow * DDIM + c] : 0.0f;
    }
    if (t < TS) red[t] = 0.0f;
    __syncthreads();

    // conv
    float acc[TS][2];
    {
        float cb0 = conv_b[c0], cb1 = conv_b[c0 + 1];
        #pragma unroll
        for (int r = 0; r < TS; r++) { acc[r][0] = cb0; acc[r][1] = cb1; }
    }
    for (int i = 0; i < DDIM; i++) {
        float xv[TS + 2];
        #pragma unroll
        for (int r = 0; r < TS + 2; r++) xv[r] = xs[r][i];
        #pragma unroll
        for (int dt = 0; dt < 3; dt++) {
            float2 w = *reinterpret_cast<const float2*>(&wcT[(size_t)(i * 3 + dt) * DDIM + c0]);
            #pragma unroll
            for (int r = 0; r < TS; r++) {
                acc[r][0] = fmaf(xv[r + dt], w.x, acc[r][0]);
                acc[r][1] = fmaf(xv[r + dt], w.y, acc[r][1]);
            }
        }
    }
    // rmsnorm of conv rows
    #pragma unroll
    for (int r = 0; r < TS; r++) {
        float p = acc[r][0] * acc[r][0] + acc[r][1] * acc[r][1];
        #pragma unroll
        for (int off = 1; off < 64; off <<= 1) p += __shfl_xor(p, off, 64);
        if ((t & 63) == 0) atomicAdd(&red[r], p);
    }
    __syncthreads();
    {
        float pg0 = pre_g[c0], pg1 = pre_g[c0 + 1];
        #pragma unroll
        for (int r = 0; r < TS; r++) {
            float inv = rsqrtf(red[r] * (1.0f / DDIM) + EPSV);
            xs[r][c0]     = acc[r][0] * inv * pg0;
            xs[r][c0 + 1] = acc[r][1] * inv * pg1;
        }
    }
    __syncthreads();

    // qkv projections
    if (t < TS) { red[t] = 0.0f; red2[t] = 0.0f; }
    float aq[TS][2] = {}, ak[TS][2] = {}, av[TS][2] = {};
    for (int d = 0; d < DDIM; d++) {
        float xv[TS];
        #pragma unroll
        for (int r = 0; r < TS; r++) xv[r] = xs[r][d];
        float2 wq = *reinterpret_cast<const float2*>(&wqT[(size_t)d * DDIM + c0]);
        float2 wk = *reinterpret_cast<const float2*>(&wkT[(size_t)d * DDIM + c0]);
        float2 wv = *reinterpret_cast<const float2*>(&wvT[(size_t)d * DDIM + c0]);
        #pragma unroll
        for (int r = 0; r < TS; r++) {
            aq[r][0] = fmaf(xv[r], wq.x, aq[r][0]); aq[r][1] = fmaf(xv[r], wq.y, aq[r][1]);
            ak[r][0] = fmaf(xv[r], wk.x, ak[r][0]); ak[r][1] = fmaf(xv[r], wk.y, ak[r][1]);
            av[r][0] = fmaf(xv[r], wv.x, av[r][0]); av[r][1] = fmaf(xv[r], wv.y, av[r][1]);
        }
    }
    // store v (bf16)
    {
        ushort_t* vb = v_out + ((size_t)b * SS + s0) * DDIM;
        #pragma unroll
        for (int r = 0; r < TS; r++)
            *reinterpret_cast<unsigned int*>(&vb[(size_t)r * DDIM + c0]) = packbf(av[r][0], av[r][1]);
    }
    __syncthreads();
    // rmsnorm q, k
    #pragma unroll
    for (int r = 0; r < TS; r++) {
        float pq = aq[r][0] * aq[r][0] + aq[r][1] * aq[r][1];
        float pk = ak[r][0] * ak[r][0] + ak[r][1] * ak[r][1];
        #pragma unroll
        for (int off = 1; off < 64; off <<= 1) {
            pq += __shfl_xor(pq, off, 64);
            pk += __shfl_xor(pk, off, 64);
        }
        if ((t & 63) == 0) { atomicAdd(&red[r], pq); atomicAdd(&red2[r], pk); }
    }
    __syncthreads();
    // rope + bf16 stores (q,k row-major — MFMA consumes both row-major)
    float invf = (float)pow(10000.0, -(double)(2 * t) / (double)DDIM);
    float qg0 = q_g[c0], qg1 = q_g[c0 + 1];
    float kg0 = k_g[c0], kg1 = k_g[c0 + 1];
    ushort_t* qb = q_out + ((size_t)b * SS + s0) * DDIM;
    ushort_t* kb = k_out + ((size_t)b * SS + s0) * DDIM;
    #pragma unroll
    for (int r = 0; r < TS; r++) {
        float invq = rsqrtf(red[r] * (1.0f / DDIM) + EPSV);
        float invk = rsqrtf(red2[r] * (1.0f / DDIM) + EPSV);
        float q0 = aq[r][0] * invq * qg0, q1 = aq[r][1] * invq * qg1;
        float kk0 = ak[r][0] * invk * kg0, kk1 = ak[r][1] * invk * kg1;
        float fr = (float)(s0 + r) * invf;
        float sn, cs;
        sincosf(fr, &sn, &cs);
        *reinterpret_cast<unsigned int*>(&qb[(size_t)r * DDIM + c0]) =
            packbf(q0 * cs - q1 * sn, q0 * sn + q1 * cs);
        *reinterpret_cast<unsigned int*>(&kb[(size_t)r * DDIM + c0]) =
            packbf(kk0 * cs - kk1 * sn, kk0 * sn + kk1 * cs);
    }
}

// ---------- shared MFMA score-GEMM machinery ----------
// 128x128 C-tile per 256-thread block (4 waves, each 64x64), BK=32, LDS pad +8 bf16.
#define LDP 40   // padded row length in bf16 elements (32 + 8)

__device__ inline short8 ldfrag(const ushort_t* s, int row, int ko) {
    return *reinterpret_cast<const short8*>(&s[row * LDP + ko]);
}

// ---------- k2a: scores GEMM + row sums of exp -> l ----------
__global__ __launch_bounds__(256, 4) void k2a_rowsum(
    const ushort_t* __restrict__ qb, const ushort_t* __restrict__ kb,
    float* __restrict__ l)
{
    __shared__ ushort_t As[128 * LDP];
    __shared__ ushort_t Bs[128 * LDP];
    const int t = threadIdx.x;
    const int lane = t & 63, w = t >> 6;
    const int lm = lane & 15, lq = lane >> 4;
    const int wm = w >> 1, wn = w & 1;
    const int srow = t >> 2;              // 0..63
    const int scol = (t & 3) * 8;         // bf16 offset within BK row

    const ushort_t* Ag = qb + ((size_t)blockIdx.z * SS + blockIdx.x * 128) * DDIM;
    const ushort_t* Bg = kb + ((size_t)blockIdx.z * SS + blockIdx.y * 128) * DDIM;

    f32x4 acc[4][4];
    #pragma unroll
    for (int i = 0; i < 4; i++)
        #pragma unroll
        for (int j = 0; j < 4; j++) acc[i][j] = (f32x4){0.f, 0.f, 0.f, 0.f};

    uint4 ra0 = *reinterpret_cast<const uint4*>(&Ag[(size_t)srow * DDIM + scol]);
    uint4 ra1 = *reinterpret_cast<const uint4*>(&Ag[(size_t)(srow + 64) * DDIM + scol]);
    uint4 rb0 = *reinterpret_cast<const uint4*>(&Bg[(size_t)srow * DDIM + scol]);
    uint4 rb1 = *reinterpret_cast<const uint4*>(&Bg[(size_t)(srow + 64) * DDIM + scol]);

    for (int dc = 0; dc < 16; dc++) {
        *reinterpret_cast<uint4*>(&As[srow * LDP + scol]) = ra0;
        *reinterpret_cast<uint4*>(&As[(srow + 64) * LDP + scol]) = ra1;
        *reinterpret_cast<uint4*>(&Bs[srow * LDP + scol]) = rb0;
        *reinterpret_cast<uint4*>(&Bs[(srow + 64) * LDP + scol]) = rb1;
        __syncthreads();
        if (dc < 15) {
            int off = (dc + 1) * 32 + scol;
            ra0 = *reinterpret_cast<const uint4*>(&Ag[(size_t)srow * DDIM + off]);
            ra1 = *reinterpret_cast<const uint4*>(&Ag[(size_t)(srow + 64) * DDIM + off]);
            rb0 = *reinterpret_cast<const uint4*>(&Bg[(size_t)srow * DDIM + off]);
            rb1 = *reinterpret_cast<const uint4*>(&Bg[(size_t)(srow + 64) * DDIM + off]);
        }
        short8 af[4];
        #pragma unroll
        for (int mt = 0; mt < 4; mt++)
            af[mt] = ldfrag(As, wm * 64 + mt * 16 + lm, lq * 8);
        #pragma unroll
        for (int nt = 0; nt < 4; nt++) {
            short8 bfv = ldfrag(Bs, wn * 64 + nt * 16 + lm, lq * 8);
            #pragma unroll
            for (int mt = 0; mt < 4; mt++)
                acc[mt][nt] = __builtin_amdgcn_mfma_f32_16x16x32_bf16(af[mt], bfv, acc[mt][nt], 0, 0, 0);
        }
        __syncthreads();
    }

    // row sums of exp(score) — no max needed: |score| <= sqrt(D) = 22.63
    float* lrow = l + (size_t)blockIdx.z * SS + blockIdx.x * 128 + wm * 64;
    #pragma unroll
    for (int mt = 0; mt < 4; mt++) {
        #pragma unroll
        for (int r = 0; r < 4; r++) {
            float p = __expf(acc[mt][0][r] * SCALE) + __expf(acc[mt][1][r] * SCALE)
                    + __expf(acc[mt][2][r] * SCALE) + __expf(acc[mt][3][r] * SCALE);
            #pragma unroll
            for (int off = 1; off < 16; off <<= 1) p += __shfl_xor(p, off, 64);
            if (lm == 0) atomicAdd(&lrow[mt * 16 + lq * 4 + r], p);
        }
    }
}

// ---------- k2b: scores GEMM + column sums of exp/l -> cw ----------
__global__ __launch_bounds__(256, 4) void k2b_colsum(
    const ushort_t* __restrict__ qb, const ushort_t* __restrict__ kb,
    const float* __restrict__ l, float* __restrict__ cw)
{
    __shared__ ushort_t As[128 * LDP];
    __shared__ ushort_t Bs[128 * LDP];
    const int t = threadIdx.x;
    const int lane = t & 63, w = t >> 6;
    const int lm = lane & 15, lq = lane >> 4;
    const int wm = w >> 1, wn = w & 1;
    const int srow = t >> 2;
    const int scol = (t & 3) * 8;

    const ushort_t* Ag = qb + ((size_t)blockIdx.z * SS + blockIdx.x * 128) * DDIM;
    const ushort_t* Bg = kb + ((size_t)blockIdx.z * SS + blockIdx.y * 128) * DDIM;

    f32x4 acc[4][4];
    #pragma unroll
    for (int i = 0; i < 4; i++)
        #pragma unroll
        for (int j = 0; j < 4; j++) acc[i][j] = (f32x4){0.f, 0.f, 0.f, 0.f};

    uint4 ra0 = *reinterpret_cast<const uint4*>(&Ag[(size_t)srow * DDIM + scol]);
    uint4 ra1 = *reinterpret_cast<const uint4*>(&Ag[(size_t)(srow + 64) * DDIM + scol]);
    uint4 rb0 = *reinterpret_cast<const uint4*>(&Bg[(size_t)srow * DDIM + scol]);
    uint4 rb1 = *reinterpret_cast<const uint4*>(&Bg[(size_t)(srow + 64) * DDIM + scol]);

    for (int dc = 0; dc < 16; dc++) {
        *reinterpret_cast<uint4*>(&As[srow * LDP + scol]) = ra0;
        *reinterpret_cast<uint4*>(&As[(srow + 64) * LDP + scol]) = ra1;
        *reinterpret_cast<uint4*>(&Bs[srow * LDP + scol]) = rb0;
        *reinterpret_cast<uint4*>(&Bs[(srow + 64) * LDP + scol]) = rb1;
        __syncthreads();
        if (dc < 15) {
            int off = (dc + 1) * 32 + scol;
            ra0 = *reinterpret_cast<const uint4*>(&Ag[(size_t)srow * DDIM + off]);
            ra1 = *reinterpret_cast<const uint4*>(&Ag[(size_t)(srow + 64) * DDIM + off]);
            rb0 = *reinterpret_cast<const uint4*>(&Bg[(size_t)srow * DDIM + off]);
            rb1 = *reinterpret_cast<const uint4*>(&Bg[(size_t)(srow + 64) * DDIM + off]);
        }
        short8 af[4];
        #pragma unroll
        for (int mt = 0; mt < 4; mt++)
            af[mt] = ldfrag(As, wm * 64 + mt * 16 + lm, lq * 8);
        #pragma unroll
        for (int nt = 0; nt < 4; nt++) {
            short8 bfv = ldfrag(Bs, wn * 64 + nt * 16 + lm, lq * 8);
            #pragma unroll
            for (int mt = 0; mt < 4; mt++)
                acc[mt][nt] = __builtin_amdgcn_mfma_f32_16x16x32_bf16(af[mt], bfv, acc[mt][nt], 0, 0, 0);
        }
        __syncthreads();
    }

    const float* lbase = l + (size_t)blockIdx.z * SS + blockIdx.x * 128 + wm * 64;
    float* cwbase = cw + (size_t)blockIdx.z * SS + blockIdx.y * 128 + wn * 64;
    float colp[4] = {0.f, 0.f, 0.f, 0.f};
    #pragma unroll
    for (int mt = 0; mt < 4; mt++) {
        #pragma unroll
        for (int r = 0; r < 4; r++) {
            float linv = 1.0f / lbase[mt * 16 + lq * 4 + r];
            #pragma unroll
            for (int nt = 0; nt < 4; nt++)
                colp[nt] = fmaf(__expf(acc[mt][nt][r] * SCALE), linv, colp[nt]);
        }
    }
    #pragma unroll
    for (int nt = 0; nt < 4; nt++) {
        float c = colp[nt];
        c += __shfl_xor(c, 16, 64);
        c += __shfl_xor(c, 32, 64);
        if (lq == 0) atomicAdd(&cwbase[nt * 16 + lm], c);
    }
}

// ---------- k4: out = (sum_s x + sum_k cw*v) / S ----------
__global__ __launch_bounds__(256) void k4_out(
    const float* __restrict__ x, const ushort_t* __restrict__ v,
    const float* __restrict__ cwv, float* __restrict__ out)
{
    const int b = blockIdx.x, c = blockIdx.y;
    const int t = threadIdx.x;
    const int srow0 = c * (SS / 16);
    const float* xb    = x + ((size_t)b * SS + srow0) * DDIM;
    const ushort_t* vb = v + ((size_t)b * SS + srow0) * DDIM;
    const float* cwb   = cwv + (size_t)b * SS + srow0;
    float a0 = 0.f, a1 = 0.f;
    for (int r = 0; r < SS / 16; r++) {
        float w = cwb[r];
        a0 += xb[(size_t)r * DDIM + t]       + w * bf2f(vb[(size_t)r * DDIM + t]);
        a1 += xb[(size_t)r * DDIM + t + 256] + w * bf2f(vb[(size_t)r * DDIM + t + 256]);
    }
    atomicAdd(&out[b * DDIM + t],       a0 * (1.0f / SS));
    atomicAdd(&out[b * DDIM + t + 256], a1 * (1.0f / SS));
}

extern "C" void kernel_launch(void* const* d_in, const int* in_sizes, int n_in,
                              void* d_out, int out_size, void* d_ws, size_t ws_size,
                              hipStream_t stream)
{
    const float* x      = (const float*)d_in[0];
    const float* conv_w = (const float*)d_in[1];
    const float* conv_b = (const float*)d_in[2];
    const float* pre_g  = (const float*)d_in[3];
    const float* q_g    = (const float*)d_in[4];
    const float* k_g    = (const float*)d_in[5];
    const float* Wq     = (const float*)d_in[6];
    const float* Wk     = (const float*)d_in[7];
    const float* Wv     = (const float*)d_in[8];
    float* out          = (float*)d_out;

    char* p = (char*)d_ws;
    float* wcT  = (float*)p; p += (size_t)DDIM * DDIM * 3 * 4;
    float* wqT  = (float*)p; p += (size_t)DDIM * DDIM * 4;
    float* wkT  = (float*)p; p += (size_t)DDIM * DDIM * 4;
    float* wvT  = (float*)p; p += (size_t)DDIM * DDIM * 4;
    ushort_t* qb = (ushort_t*)p; p += (size_t)BB * SS * DDIM * 2;
    ushort_t* kb = (ushort_t*)p; p += (size_t)BB * SS * DDIM * 2;
    ushort_t* vb = (ushort_t*)p; p += (size_t)BB * SS * DDIM * 2;
    float* lbuf = (float*)p; p += (size_t)BB * SS * 4;
    float* cwb  = (float*)p; p += (size_t)BB * SS * 4;

    (void)hipMemsetAsync(d_out, 0, (size_t)out_size * sizeof(float), stream);
    (void)hipMemsetAsync(lbuf, 0, (size_t)BB * SS * 2 * sizeof(float), stream);  // l + cw contiguous

    k0_prep<<<dim3((DDIM * DDIM * 3 + 255) / 256), 256, 0, stream>>>(
        conv_w, Wq, Wk, Wv, wcT, wqT, wkT, wvT);
    k1_conv_qkv<<<dim3(SS / TS, BB), 256, 0, stream>>>(
        x, conv_b, pre_g, q_g, k_g, wcT, wqT, wkT, wvT, qb, kb, vb);
    k2a_rowsum<<<dim3(SS / 128, SS / 128, BB), 256, 0, stream>>>(qb, kb, lbuf);
    k2b_colsum<<<dim3(SS / 128, SS / 128, BB), 256, 0, stream>>>(qb, kb, lbuf, cwb);
    k4_out<<<dim3(BB, 16), 256, 0, stream>>>(x, vb, cwb, out);
}

// Round 4
// 324.332 us; speedup vs baseline: 7.2649x; 3.1667x over previous
//
#include <hip/hip_runtime.h>
#include <math.h>

#define BB 8
#define SS 2048
#define DDIM 512
#define KC 1536
#define EPSV 1e-6f
#define SCALE 0.044194173824159216f   // 1/sqrt(512)
#define LDP 40   // padded LDS row (32 + 8 bf16)

typedef unsigned short ushort_t;
using short8 = __attribute__((ext_vector_type(8))) short;
using f32x4  = __attribute__((ext_vector_type(4))) float;

__device__ inline unsigned short f2bf(float f) {
    union { float f; unsigned int u; } v; v.f = f;
    unsigned int r = v.u + 0x7FFFu + ((v.u >> 16) & 1u);   // RNE
    return (unsigned short)(r >> 16);
}
__device__ inline unsigned int packbf(float a, float b) {
    return (unsigned int)f2bf(a) | ((unsigned int)f2bf(b) << 16);
}
__device__ inline float bf2f(unsigned short s) {
    union { unsigned int u; float f; } v; v.u = ((unsigned int)s) << 16; return v.f;
}
__device__ inline short8 ldfrag(const ushort_t* s, int row, int ko) {
    return *reinterpret_cast<const short8*>(&s[row * LDP + ko]);
}

// ---------- kx: x fp32 -> bf16 ----------
__global__ __launch_bounds__(256) void kx_cast(const float* __restrict__ x, ushort_t* __restrict__ xbf)
{
    int i = (blockIdx.x * 256 + threadIdx.x) * 4;
    float4 v = *reinterpret_cast<const float4*>(&x[i]);
    unsigned int lo = packbf(v.x, v.y), hi = packbf(v.z, v.w);
    *reinterpret_cast<uint2*>(&xbf[i]) = make_uint2(lo, hi);
}

// ---------- k0: weights -> bf16 (wcat for conv-as-GEMM, wqkv concat) ----------
__global__ __launch_bounds__(256) void k0_prep(
    const float* __restrict__ conv_w, const float* __restrict__ Wq,
    const float* __restrict__ Wk, const float* __restrict__ Wv,
    ushort_t* __restrict__ wcat, ushort_t* __restrict__ wqkv)
{
    int idx = blockIdx.x * 256 + threadIdx.x;   // < 512*1536
    {   // wcat[o][t*512+i] = conv_w[o][i][t]
        int o = idx / KC, kk = idx - o * KC;
        int t = kk >> 9, i = kk & 511;
        wcat[idx] = f2bf(conv_w[(size_t)o * KC + i * 3 + t]);
    }
    {   // wqkv[n][d], n<512: Wq ; n<1024: Wk ; else Wv
        int n = idx >> 9, d = idx & 511;
        const float* src = (n < 512) ? &Wq[(size_t)n * DDIM + d]
                         : (n < 1024) ? &Wk[(size_t)(n - 512) * DDIM + d]
                         : &Wv[(size_t)(n - 1024) * DDIM + d];
        wqkv[idx] = f2bf(*src);
    }
}

// ---------- k1b: conv as MFMA GEMM (K=1536 im2col via shifted rows) ----------
__global__ __launch_bounds__(256, 4) void k1b_conv(
    const ushort_t* __restrict__ xbf, const ushort_t* __restrict__ wcat,
    const float* __restrict__ conv_b, float* __restrict__ y, float* __restrict__ rs)
{
    __shared__ ushort_t As[128 * LDP];
    __shared__ ushort_t Bs[128 * LDP];
    const int t = threadIdx.x;
    const int lane = t & 63, w = t >> 6;
    const int lm = lane & 15, lq = lane >> 4;
    const int wm = w >> 1, wn = w & 1;
    const int srow = t >> 2, scol = (t & 3) * 8;
    const int s0 = blockIdx.x * 128;
    const int n0 = blockIdx.y * 128;
    const int b  = blockIdx.z;
    const ushort_t* Ag = xbf + (size_t)b * SS * DDIM;
    const ushort_t* Bg = wcat + (size_t)n0 * KC;

    f32x4 acc[4][4];
    #pragma unroll
    for (int i = 0; i < 4; i++)
        #pragma unroll
        for (int j = 0; j < 4; j++) acc[i][j] = (f32x4){0.f, 0.f, 0.f, 0.f};

    const uint4 z4 = make_uint4(0, 0, 0, 0);
    #define LOADA(dc, ro, dst) { \
        int s_ = s0 + srow + (ro) + ((dc) >> 4) - 1; \
        int ic_ = (((dc) & 15) << 5) + scol; \
        dst = (s_ >= 0 && s_ < SS) ? *reinterpret_cast<const uint4*>(&Ag[(size_t)s_ * DDIM + ic_]) : z4; }

    uint4 ra0, ra1, rb0, rb1;
    LOADA(0, 0, ra0); LOADA(0, 64, ra1);
    rb0 = *reinterpret_cast<const uint4*>(&Bg[(size_t)srow * KC + scol]);
    rb1 = *reinterpret_cast<const uint4*>(&Bg[(size_t)(srow + 64) * KC + scol]);

    for (int dc = 0; dc < 48; dc++) {
        *reinterpret_cast<uint4*>(&As[srow * LDP + scol]) = ra0;
        *reinterpret_cast<uint4*>(&As[(srow + 64) * LDP + scol]) = ra1;
        *reinterpret_cast<uint4*>(&Bs[srow * LDP + scol]) = rb0;
        *reinterpret_cast<uint4*>(&Bs[(srow + 64) * LDP + scol]) = rb1;
        __syncthreads();
        if (dc < 47) {
            LOADA(dc + 1, 0, ra0); LOADA(dc + 1, 64, ra1);
            int c = (dc + 1) * 32 + scol;
            rb0 = *reinterpret_cast<const uint4*>(&Bg[(size_t)srow * KC + c]);
            rb1 = *reinterpret_cast<const uint4*>(&Bg[(size_t)(srow + 64) * KC + c]);
        }
        short8 af[4];
        #pragma unroll
        for (int mt = 0; mt < 4; mt++)
            af[mt] = ldfrag(As, wm * 64 + mt * 16 + lm, lq * 8);
        #pragma unroll
        for (int nt = 0; nt < 4; nt++) {
            short8 bfv = ldfrag(Bs, wn * 64 + nt * 16 + lm, lq * 8);
            #pragma unroll
            for (int mt = 0; mt < 4; mt++)
                acc[mt][nt] = __builtin_amdgcn_mfma_f32_16x16x32_bf16(af[mt], bfv, acc[mt][nt], 0, 0, 0);
        }
        __syncthreads();
    }
    #undef LOADA

    // epilogue: +bias, write y fp32, row sumsq atomics
    const int rbase = s0 + wm * 64;
    const int cbase = n0 + wn * 64;
    float* yb  = y + (size_t)b * SS * DDIM;
    float* rsb = rs + (size_t)b * SS;
    float bias[4];
    #pragma unroll
    for (int nt = 0; nt < 4; nt++) bias[nt] = conv_b[cbase + nt * 16 + lm];
    #pragma unroll
    for (int mt = 0; mt < 4; mt++) {
        float pr[4] = {0.f, 0.f, 0.f, 0.f};
        #pragma unroll
        for (int nt = 0; nt < 4; nt++) {
            #pragma unroll
            for (int r = 0; r < 4; r++) {
                float val = acc[mt][nt][r] + bias[nt];
                yb[(size_t)(rbase + mt * 16 + lq * 4 + r) * DDIM + cbase + nt * 16 + lm] = val;
                pr[r] = fmaf(val, val, pr[r]);
            }
        }
        #pragma unroll
        for (int r = 0; r < 4; r++) {
            float p = pr[r];
            p += __shfl_xor(p, 1, 64); p += __shfl_xor(p, 2, 64);
            p += __shfl_xor(p, 4, 64); p += __shfl_xor(p, 8, 64);
            if (lm == 0) atomicAdd(&rsb[rbase + mt * 16 + lq * 4 + r], p);
        }
    }
}

// ---------- k1n: x_norm = y * rsqrt(rs/D+eps) * pre_g  -> bf16 ----------
__global__ __launch_bounds__(256) void k1n_norm(
    const float* __restrict__ y, const float* __restrict__ rs,
    const float* __restrict__ pre_g, ushort_t* __restrict__ xnbf)
{
    const int t = threadIdx.x;
    const int b = blockIdx.y;
    const int r0 = blockIdx.x * 8;
    float2 pg = *reinterpret_cast<const float2*>(&pre_g[2 * t]);
    for (int r = 0; r < 8; r++) {
        size_t row = (size_t)b * SS + r0 + r;
        float inv = rsqrtf(rs[row] * (1.0f / DDIM) + EPSV);
        float2 v = *reinterpret_cast<const float2*>(&y[row * DDIM + 2 * t]);
        *reinterpret_cast<unsigned int*>(&xnbf[row * DDIM + 2 * t]) =
            packbf(v.x * inv * pg.x, v.y * inv * pg.y);
    }
}

// ---------- k1c: QKV GEMM (N=1536 concat) ----------
__global__ __launch_bounds__(256, 4) void k1c_qkv(
    const ushort_t* __restrict__ xnbf, const ushort_t* __restrict__ wqkv,
    float* __restrict__ qraw, float* __restrict__ kraw, ushort_t* __restrict__ vb,
    float* __restrict__ rq, float* __restrict__ rk)
{
    __shared__ ushort_t As[128 * LDP];
    __shared__ ushort_t Bs[128 * LDP];
    const int t = threadIdx.x;
    const int lane = t & 63, w = t >> 6;
    const int lm = lane & 15, lq = lane >> 4;
    const int wm = w >> 1, wn = w & 1;
    const int srow = t >> 2, scol = (t & 3) * 8;
    const int s0 = blockIdx.x * 128;
    const int n0 = blockIdx.y * 128;
    const int b  = blockIdx.z;
    const ushort_t* Ag = xnbf + (size_t)b * SS * DDIM;
    const ushort_t* Bg = wqkv + (size_t)n0 * DDIM;

    f32x4 acc[4][4];
    #pragma unroll
    for (int i = 0; i < 4; i++)
        #pragma unroll
        for (int j = 0; j < 4; j++) acc[i][j] = (f32x4){0.f, 0.f, 0.f, 0.f};

    uint4 ra0 = *reinterpret_cast<const uint4*>(&Ag[(size_t)(s0 + srow) * DDIM + scol]);
    uint4 ra1 = *reinterpret_cast<const uint4*>(&Ag[(size_t)(s0 + srow + 64) * DDIM + scol]);
    uint4 rb0 = *reinterpret_cast<const uint4*>(&Bg[(size_t)srow * DDIM + scol]);
    uint4 rb1 = *reinterpret_cast<const uint4*>(&Bg[(size_t)(srow + 64) * DDIM + scol]);

    for (int dc = 0; dc < 16; dc++) {
        *reinterpret_cast<uint4*>(&As[srow * LDP + scol]) = ra0;
        *reinterpret_cast<uint4*>(&As[(srow + 64) * LDP + scol]) = ra1;
        *reinterpret_cast<uint4*>(&Bs[srow * LDP + scol]) = rb0;
        *reinterpret_cast<uint4*>(&Bs[(srow + 64) * LDP + scol]) = rb1;
        __syncthreads();
        if (dc < 15) {
            int c = (dc + 1) * 32 + scol;
            ra0 = *reinterpret_cast<const uint4*>(&Ag[(size_t)(s0 + srow) * DDIM + c]);
            ra1 = *reinterpret_cast<const uint4*>(&Ag[(size_t)(s0 + srow + 64) * DDIM + c]);
            rb0 = *reinterpret_cast<const uint4*>(&Bg[(size_t)srow * DDIM + c]);
            rb1 = *reinterpret_cast<const uint4*>(&Bg[(size_t)(srow + 64) * DDIM + c]);
        }
        short8 af[4];
        #pragma unroll
        for (int mt = 0; mt < 4; mt++)
            af[mt] = ldfrag(As, wm * 64 + mt * 16 + lm, lq * 8);
        #pragma unroll
        for (int nt = 0; nt < 4; nt++) {
            short8 bfv = ldfrag(Bs, wn * 64 + nt * 16 + lm, lq * 8);
            #pragma unroll
            for (int mt = 0; mt < 4; mt++)
                acc[mt][nt] = __builtin_amdgcn_mfma_f32_16x16x32_bf16(af[mt], bfv, acc[mt][nt], 0, 0, 0);
        }
        __syncthreads();
    }

    const int which = blockIdx.y >> 2;              // 0=q 1=k 2=v
    const int rbase = s0 + wm * 64;
    const int cbase = ((blockIdx.y & 3) * 128) + wn * 64;
    if (which == 2) {
        ushort_t* vbb = vb + (size_t)b * SS * DDIM;
        #pragma unroll
        for (int mt = 0; mt < 4; mt++)
            #pragma unroll
            for (int nt = 0; nt < 4; nt++)
                #pragma unroll
                for (int r = 0; r < 4; r++)
                    vbb[(size_t)(rbase + mt * 16 + lq * 4 + r) * DDIM + cbase + nt * 16 + lm] =
                        f2bf(acc[mt][nt][r]);
    } else {
        float* dst = which ? kraw : qraw;
        float* rr  = which ? rk : rq;
        float* db  = dst + (size_t)b * SS * DDIM;
        float* rb  = rr + (size_t)b * SS;
        #pragma unroll
        for (int mt = 0; mt < 4; mt++) {
            float pr[4] = {0.f, 0.f, 0.f, 0.f};
            #pragma unroll
            for (int nt = 0; nt < 4; nt++) {
                #pragma unroll
                for (int r = 0; r < 4; r++) {
                    float val = acc[mt][nt][r];
                    db[(size_t)(rbase + mt * 16 + lq * 4 + r) * DDIM + cbase + nt * 16 + lm] = val;
                    pr[r] = fmaf(val, val, pr[r]);
                }
            }
            #pragma unroll
            for (int r = 0; r < 4; r++) {
                float p = pr[r];
                p += __shfl_xor(p, 1, 64); p += __shfl_xor(p, 2, 64);
                p += __shfl_xor(p, 4, 64); p += __shfl_xor(p, 8, 64);
                if (lm == 0) atomicAdd(&rb[rbase + mt * 16 + lq * 4 + r], p);
            }
        }
    }
}

// ---------- k1d: rmsnorm(q,k) + rope -> bf16 ----------
__global__ __launch_bounds__(256) void k1d_rope(
    const float* __restrict__ qraw, const float* __restrict__ kraw,
    const float* __restrict__ rq, const float* __restrict__ rk,
    const float* __restrict__ q_g, const float* __restrict__ k_g,
    ushort_t* __restrict__ qb, ushort_t* __restrict__ kb)
{
    const int t = threadIdx.x;
    const int b = blockIdx.y;
    const int r0 = blockIdx.x * 8;
    const int c0 = 2 * t;
    float qg0 = q_g[c0], qg1 = q_g[c0 + 1];
    float kg0 = k_g[c0], kg1 = k_g[c0 + 1];
    float invf = (float)pow(10000.0, -(double)c0 / (double)DDIM);
    for (int r = 0; r < 8; r++) {
        int srow = r0 + r;
        size_t rowi = (size_t)b * SS + srow;
        float iq = rsqrtf(rq[rowi] * (1.0f / DDIM) + EPSV);
        float ik = rsqrtf(rk[rowi] * (1.0f / DDIM) + EPSV);
        size_t off = rowi * DDIM + c0;
        float2 qv = *reinterpret_cast<const float2*>(&qraw[off]);
        float2 kv = *reinterpret_cast<const float2*>(&kraw[off]);
        float q0 = qv.x * iq * qg0, q1 = qv.y * iq * qg1;
        float k0v = kv.x * ik * kg0, k1v = kv.y * ik * kg1;
        float ang = (float)srow * invf, sn, cs;
        sincosf(ang, &sn, &cs);
        *reinterpret_cast<unsigned int*>(&qb[off]) = packbf(q0 * cs - q1 * sn, q0 * sn + q1 * cs);
        *reinterpret_cast<unsigned int*>(&kb[off]) = packbf(k0v * cs - k1v * sn, k0v * sn + k1v * cs);
    }
}

// ---------- k2a: scores GEMM + row sums of exp -> l ----------
__global__ __launch_bounds__(256, 4) void k2a_rowsum(
    const ushort_t* __restrict__ qb, const ushort_t* __restrict__ kb,
    float* __restrict__ l)
{
    __shared__ ushort_t As[128 * LDP];
    __shared__ ushort_t Bs[128 * LDP];
    const int t = threadIdx.x;
    const int lane = t & 63, w = t >> 6;
    const int lm = lane & 15, lq = lane >> 4;
    const int wm = w >> 1, wn = w & 1;
    const int srow = t >> 2;
    const int scol = (t & 3) * 8;

    const ushort_t* Ag = qb + ((size_t)blockIdx.z * SS + blockIdx.x * 128) * DDIM;
    const ushort_t* Bg = kb + ((size_t)blockIdx.z * SS + blockIdx.y * 128) * DDIM;

    f32x4 acc[4][4];
    #pragma unroll
    for (int i = 0; i < 4; i++)
        #pragma unroll
        for (int j = 0; j < 4; j++) acc[i][j] = (f32x4){0.f, 0.f, 0.f, 0.f};

    uint4 ra0 = *reinterpret_cast<const uint4*>(&Ag[(size_t)srow * DDIM + scol]);
    uint4 ra1 = *reinterpret_cast<const uint4*>(&Ag[(size_t)(srow + 64) * DDIM + scol]);
    uint4 rb0 = *reinterpret_cast<const uint4*>(&Bg[(size_t)srow * DDIM + scol]);
    uint4 rb1 = *reinterpret_cast<const uint4*>(&Bg[(size_t)(srow + 64) * DDIM + scol]);

    for (int dc = 0; dc < 16; dc++) {
        *reinterpret_cast<uint4*>(&As[srow * LDP + scol]) = ra0;
        *reinterpret_cast<uint4*>(&As[(srow + 64) * LDP + scol]) = ra1;
        *reinterpret_cast<uint4*>(&Bs[srow * LDP + scol]) = rb0;
        *reinterpret_cast<uint4*>(&Bs[(srow + 64) * LDP + scol]) = rb1;
        __syncthreads();
        if (dc < 15) {
            int off = (dc + 1) * 32 + scol;
            ra0 = *reinterpret_cast<const uint4*>(&Ag[(size_t)srow * DDIM + off]);
            ra1 = *reinterpret_cast<const uint4*>(&Ag[(size_t)(srow + 64) * DDIM + off]);
            rb0 = *reinterpret_cast<const uint4*>(&Bg[(size_t)srow * DDIM + off]);
            rb1 = *reinterpret_cast<const uint4*>(&Bg[(size_t)(srow + 64) * DDIM + off]);
        }
        short8 af[4];
        #pragma unroll
        for (int mt = 0; mt < 4; mt++)
            af[mt] = ldfrag(As, wm * 64 + mt * 16 + lm, lq * 8);
        #pragma unroll
        for (int nt = 0; nt < 4; nt++) {
            short8 bfv = ldfrag(Bs, wn * 64 + nt * 16 + lm, lq * 8);
            #pragma unroll
            for (int mt = 0; mt < 4; mt++)
                acc[mt][nt] = __builtin_amdgcn_mfma_f32_16x16x32_bf16(af[mt], bfv, acc[mt][nt], 0, 0, 0);
        }
        __syncthreads();
    }

    float* lrow = l + (size_t)blockIdx.z * SS + blockIdx.x * 128 + wm * 64;
    #pragma unroll
    for (int mt = 0; mt < 4; mt++) {
        #pragma unroll
        for (int r = 0; r < 4; r++) {
            float p = __expf(acc[mt][0][r] * SCALE) + __expf(acc[mt][1][r] * SCALE)
                    + __expf(acc[mt][2][r] * SCALE) + __expf(acc[mt][3][r] * SCALE);
            #pragma unroll
            for (int off = 1; off < 16; off <<= 1) p += __shfl_xor(p, off, 64);
            if (lm == 0) atomicAdd(&lrow[mt * 16 + lq * 4 + r], p);
        }
    }
}

// ---------- k2b: scores GEMM + column sums of exp/l -> cw ----------
__global__ __launch_bounds__(256, 4) void k2b_colsum(
    const ushort_t* __restrict__ qb, const ushort_t* __restrict__ kb,
    const float* __restrict__ l, float* __restrict__ cw)
{
    __shared__ ushort_t As[128 * LDP];
    __shared__ ushort_t Bs[128 * LDP];
    const int t = threadIdx.x;
    const int lane = t & 63, w = t >> 6;
    const int lm = lane & 15, lq = lane >> 4;
    const int wm = w >> 1, wn = w & 1;
    const int srow = t >> 2;
    const int scol = (t & 3) * 8;

    const ushort_t* Ag = qb + ((size_t)blockIdx.z * SS + blockIdx.x * 128) * DDIM;
    const ushort_t* Bg = kb + ((size_t)blockIdx.z * SS + blockIdx.y * 128) * DDIM;

    f32x4 acc[4][4];
    #pragma unroll
    for (int i = 0; i < 4; i++)
        #pragma unroll
        for (int j = 0; j < 4; j++) acc[i][j] = (f32x4){0.f, 0.f, 0.f, 0.f};

    uint4 ra0 = *reinterpret_cast<const uint4*>(&Ag[(size_t)srow * DDIM + scol]);
    uint4 ra1 = *reinterpret_cast<const uint4*>(&Ag[(size_t)(srow + 64) * DDIM + scol]);
    uint4 rb0 = *reinterpret_cast<const uint4*>(&Bg[(size_t)srow * DDIM + scol]);
    uint4 rb1 = *reinterpret_cast<const uint4*>(&Bg[(size_t)(srow + 64) * DDIM + scol]);

    for (int dc = 0; dc < 16; dc++) {
        *reinterpret_cast<uint4*>(&As[srow * LDP + scol]) = ra0;
        *reinterpret_cast<uint4*>(&As[(srow + 64) * LDP + scol]) = ra1;
        *reinterpret_cast<uint4*>(&Bs[srow * LDP + scol]) = rb0;
        *reinterpret_cast<uint4*>(&Bs[(srow + 64) * LDP + scol]) = rb1;
        __syncthreads();
        if (dc < 15) {
            int off = (dc + 1) * 32 + scol;
            ra0 = *reinterpret_cast<const uint4*>(&Ag[(size_t)srow * DDIM + off]);
            ra1 = *reinterpret_cast<const uint4*>(&Ag[(size_t)(srow + 64) * DDIM + off]);
            rb0 = *reinterpret_cast<const uint4*>(&Bg[(size_t)srow * DDIM + off]);
            rb1 = *reinterpret_cast<const uint4*>(&Bg[(size_t)(srow + 64) * DDIM + off]);
        }
        short8 af[4];
        #pragma unroll
        for (int mt = 0; mt < 4; mt++)
            af[mt] = ldfrag(As, wm * 64 + mt * 16 + lm, lq * 8);
        #pragma unroll
        for (int nt = 0; nt < 4; nt++) {
            short8 bfv = ldfrag(Bs, wn * 64 + nt * 16 + lm, lq * 8);
            #pragma unroll
            for (int mt = 0; mt < 4; mt++)
                acc[mt][nt] = __builtin_amdgcn_mfma_f32_16x16x32_bf16(af[mt], bfv, acc[mt][nt], 0, 0, 0);
        }
        __syncthreads();
    }

    const float* lbase = l + (size_t)blockIdx.z * SS + blockIdx.x * 128 + wm * 64;
    float* cwbase = cw + (size_t)blockIdx.z * SS + blockIdx.y * 128 + wn * 64;
    float colp[4] = {0.f, 0.f, 0.f, 0.f};
    #pragma unroll
    for (int mt = 0; mt < 4; mt++) {
        #pragma unroll
        for (int r = 0; r < 4; r++) {
            float linv = 1.0f / lbase[mt * 16 + lq * 4 + r];
            #pragma unroll
            for (int nt = 0; nt < 4; nt++)
                colp[nt] = fmaf(__expf(acc[mt][nt][r] * SCALE), linv, colp[nt]);
        }
    }
    #pragma unroll
    for (int nt = 0; nt < 4; nt++) {
        float c = colp[nt];
        c += __shfl_xor(c, 16, 64);
        c += __shfl_xor(c, 32, 64);
        if (lq == 0) atomicAdd(&cwbase[nt * 16 + lm], c);
    }
}

// ---------- k4: out = (sum_s x + sum_k cw*v) / S ----------
__global__ __launch_bounds__(256) void k4_out(
    const float* __restrict__ x, const ushort_t* __restrict__ v,
    const float* __restrict__ cwv, float* __restrict__ out)
{
    const int b = blockIdx.x, c = blockIdx.y;
    const int t = threadIdx.x;
    const int srow0 = c * (SS / 16);
    const float* xb    = x + ((size_t)b * SS + srow0) * DDIM;
    const ushort_t* vb = v + ((size_t)b * SS + srow0) * DDIM;
    const float* cwb   = cwv + (size_t)b * SS + srow0;
    float a0 = 0.f, a1 = 0.f;
    for (int r = 0; r < SS / 16; r++) {
        float w = cwb[r];
        a0 += xb[(size_t)r * DDIM + t]       + w * bf2f(vb[(size_t)r * DDIM + t]);
        a1 += xb[(size_t)r * DDIM + t + 256] + w * bf2f(vb[(size_t)r * DDIM + t + 256]);
    }
    atomicAdd(&out[b * DDIM + t],       a0 * (1.0f / SS));
    atomicAdd(&out[b * DDIM + t + 256], a1 * (1.0f / SS));
}

extern "C" void kernel_launch(void* const* d_in, const int* in_sizes, int n_in,
                              void* d_out, int out_size, void* d_ws, size_t ws_size,
                              hipStream_t stream)
{
    const float* x      = (const float*)d_in[0];
    const float* conv_w = (const float*)d_in[1];
    const float* conv_b = (const float*)d_in[2];
    const float* pre_g  = (const float*)d_in[3];
    const float* q_g    = (const float*)d_in[4];
    const float* k_g    = (const float*)d_in[5];
    const float* Wq     = (const float*)d_in[6];
    const float* Wk     = (const float*)d_in[7];
    const float* Wv     = (const float*)d_in[8];
    float* out          = (float*)d_out;

    const size_t NTOK = (size_t)BB * SS * DDIM;   // 8.4M
    char* p = (char*)d_ws;
    float* y_qraw  = (float*)p; p += NTOK * 4;          // y, later qraw
    float* kraw    = (float*)p; p += NTOK * 4;
    ushort_t* xbf_vb = (ushort_t*)p; p += NTOK * 2;     // xbf, later v
    ushort_t* xn_qb  = (ushort_t*)p; p += NTOK * 2;     // x_norm, later q(bf16)
    ushort_t* kb     = (ushort_t*)p; p += NTOK * 2;
    ushort_t* wcat   = (ushort_t*)p; p += (size_t)DDIM * KC * 2;
    ushort_t* wqkv   = (ushort_t*)p; p += (size_t)KC * DDIM * 2;
    float* rs   = (float*)p; p += (size_t)BB * SS * 4;
    float* rq   = (float*)p; p += (size_t)BB * SS * 4;
    float* rk   = (float*)p; p += (size_t)BB * SS * 4;
    float* lbuf = (float*)p; p += (size_t)BB * SS * 4;
    float* cwb  = (float*)p; p += (size_t)BB * SS * 4;

    (void)hipMemsetAsync(d_out, 0, (size_t)out_size * sizeof(float), stream);
    (void)hipMemsetAsync(rs, 0, (size_t)BB * SS * 5 * sizeof(float), stream);

    kx_cast<<<dim3((unsigned)(NTOK / 1024)), 256, 0, stream>>>(x, xbf_vb);
    k0_prep<<<dim3(DDIM * KC / 256), 256, 0, stream>>>(conv_w, Wq, Wk, Wv, wcat, wqkv);
    k1b_conv<<<dim3(SS / 128, 4, BB), 256, 0, stream>>>(xbf_vb, wcat, conv_b, y_qraw, rs);
    k1n_norm<<<dim3(SS / 8, BB), 256, 0, stream>>>(y_qraw, rs, pre_g, xn_qb);
    k1c_qkv<<<dim3(SS / 128, 12, BB), 256, 0, stream>>>(xn_qb, wqkv, y_qraw, kraw, xbf_vb, rq, rk);
    k1d_rope<<<dim3(SS / 8, BB), 256, 0, stream>>>(y_qraw, kraw, rq, rk, q_g, k_g, xn_qb, kb);
    k2a_rowsum<<<dim3(SS / 128, SS / 128, BB), 256, 0, stream>>>(xn_qb, kb, lbuf);
    k2b_colsum<<<dim3(SS / 128, SS / 128, BB), 256, 0, stream>>>(xn_qb, kb, lbuf, cwb);
    k4_out<<<dim3(BB, 16), 256, 0, stream>>>(x, xbf_vb, cwb, out);
}